// Round 1
// baseline (309.040 us; speedup 1.0000x reference)
//
#include <hip/hip_runtime.h>
#include <math.h>

#define T_N 2097152
#define NBLK 2048
#define NT 256
#define EPT 4
#define CHUNK (NT * EPT)          // 1024 elements per block
#define GAMMA_F 0.99f
#define GL_F (0.99f * 0.95f)
#define LOG2PI_F 1.8378770664093453f

// ws layout:
//   [0..47]                       : 6 doubles: sum_a, sumsq_a, sum_r, sumsq_r, actor_sum, critic_sum
//   [256 .. 256+NBLK*16)          : per-block affine summaries (Ar,Br,Aa,Ba)
//   [.. +NBLK*8)                  : per-block carries (ret, adv)
//   [.. +T*4)                     : adv array
//   [.. +T*4)                     : ret array

// Inclusive suffix scan over [i, NT-1] of affine pairs for two recurrences.
// compose(L, R): A = A_L*A_R, B = A_L*B_R + B_L  (L is leftward/applied last in reverse time)
__device__ __forceinline__ void block_suffix_scan(float* sAr, float* sBr,
                                                  float* sAa, float* sBa, int tid) {
    for (int s = 1; s < NT; s <<= 1) {
        float ar = sAr[tid], br = sBr[tid], aa = sAa[tid], ba = sBa[tid];
        float ar2 = 1.f, br2 = 0.f, aa2 = 1.f, ba2 = 0.f;
        int j = tid + s;
        if (j < NT) { ar2 = sAr[j]; br2 = sBr[j]; aa2 = sAa[j]; ba2 = sBa[j]; }
        __syncthreads();
        sAr[tid] = ar * ar2;  sBr[tid] = ar * br2 + br;
        sAa[tid] = aa * aa2;  sBa[tid] = aa * ba2 + ba;
        __syncthreads();
    }
}

// Build this thread's affine transform over its EPT elements (reverse order).
__device__ __forceinline__ void thread_transform(const float rr[4], const float vv[4],
                                                 const float mm[4], float vnext,
                                                 float& ar, float& br, float& aa, float& ba) {
    ar = 1.f; br = 0.f; aa = 1.f; ba = 0.f;
    float vn = vnext;
#pragma unroll
    for (int j = EPT - 1; j >= 0; --j) {
        float m = mm[j];
        float gm = GAMMA_F * m;
        br = rr[j] + gm * br;  ar = gm * ar;                    // ret: y = gm*y + r
        float delta = rr[j] + GAMMA_F * vn * m - vv[j];
        float gl = GL_F * m;
        ba = delta + gl * ba;  aa = gl * aa;                    // adv: y = gl*y + delta
        vn = vv[j];
    }
}

__global__ __launch_bounds__(NT) void k_summ(const float* __restrict__ rew,
                                             const float* __restrict__ val,
                                             const int* __restrict__ msk,
                                             float4* __restrict__ blk) {
    __shared__ float sAr[NT], sBr[NT], sAa[NT], sBa[NT];
    int tid = threadIdx.x;
    int g = blockIdx.x * CHUNK + tid * EPT;
    float4 r4 = *(const float4*)(rew + g);
    float4 v4 = *(const float4*)(val + g);
    int4 m4 = *(const int4*)(msk + g);
    float vnext = (g + EPT < T_N) ? val[g + EPT] : 0.f;
    float rr[4] = {r4.x, r4.y, r4.z, r4.w};
    float vv[4] = {v4.x, v4.y, v4.z, v4.w};
    float mm[4] = {(float)m4.x, (float)m4.y, (float)m4.z, (float)m4.w};
    float ar, br, aa, ba;
    thread_transform(rr, vv, mm, vnext, ar, br, aa, ba);
    sAr[tid] = ar; sBr[tid] = br; sAa[tid] = aa; sBa[tid] = ba;
    __syncthreads();
    block_suffix_scan(sAr, sBr, sAa, sBa, tid);
    if (tid == 0) blk[blockIdx.x] = make_float4(sAr[0], sBr[0], sAa[0], sBa[0]);
}

__global__ __launch_bounds__(NT) void k_carry(const float4* __restrict__ blk,
                                              float2* __restrict__ car,
                                              double* __restrict__ acc) {
    __shared__ float sAr[NT], sBr[NT], sAa[NT], sBa[NT];
    int tid = threadIdx.x;
    const int GPT = NBLK / NT;  // 8 block-summaries per thread
    float lar[8], lbr[8], laa[8], lba[8];
#pragma unroll
    for (int p = 0; p < GPT; ++p) {
        float4 s = blk[tid * GPT + p];
        lar[p] = s.x; lbr[p] = s.y; laa[p] = s.z; lba[p] = s.w;
    }
    // group composition (s_0 o s_1 o ... o s_7), built serially from the right
    float ar = 1.f, br = 0.f, aa = 1.f, ba = 0.f;
#pragma unroll
    for (int p = GPT - 1; p >= 0; --p) {
        br = lar[p] * br + lbr[p];  ar = lar[p] * ar;
        ba = laa[p] * ba + lba[p];  aa = laa[p] * aa;
    }
    sAr[tid] = ar; sBr[tid] = br; sAa[tid] = aa; sBa[tid] = ba;
    __syncthreads();
    block_suffix_scan(sAr, sBr, sAa, sBa, tid);
    // H = inclusive suffix composition of groups (tid+1 .. NT-1); identity for last
    float Har = 1.f, Hbr = 0.f, Haa = 1.f, Hba = 0.f;
    if (tid + 1 < NT) { Har = sAr[tid + 1]; Hbr = sBr[tid + 1]; Haa = sAa[tid + 1]; Hba = sBa[tid + 1]; }
#pragma unroll
    for (int p = GPT - 1; p >= 0; --p) {
        // carry entering block (tid*GPT+p) from the right = H applied to 0 = H.B
        car[tid * GPT + p] = make_float2(Hbr, Hba);
        Hbr = lar[p] * Hbr + lbr[p];  Har = lar[p] * Har;
        Hba = laa[p] * Hba + lba[p];  Haa = laa[p] * Haa;
    }
    if (tid == 0) {
#pragma unroll
        for (int i = 0; i < 6; ++i) acc[i] = 0.0;  // ws is poisoned each launch
    }
}

__global__ __launch_bounds__(NT) void k_scan(const float* __restrict__ rew,
                                             const float* __restrict__ val,
                                             const int* __restrict__ msk,
                                             const float2* __restrict__ car,
                                             float* __restrict__ advo,
                                             float* __restrict__ reto,
                                             double* __restrict__ acc) {
    __shared__ float sAr[NT], sBr[NT], sAa[NT], sBa[NT];
    int tid = threadIdx.x;
    int g = blockIdx.x * CHUNK + tid * EPT;
    float4 r4 = *(const float4*)(rew + g);
    float4 v4 = *(const float4*)(val + g);
    int4 m4 = *(const int4*)(msk + g);
    float vnext = (g + EPT < T_N) ? val[g + EPT] : 0.f;
    float rr[4] = {r4.x, r4.y, r4.z, r4.w};
    float vv[4] = {v4.x, v4.y, v4.z, v4.w};
    float mm[4] = {(float)m4.x, (float)m4.y, (float)m4.z, (float)m4.w};
    float ar, br, aa, ba;
    thread_transform(rr, vv, mm, vnext, ar, br, aa, ba);
    sAr[tid] = ar; sBr[tid] = br; sAa[tid] = aa; sBa[tid] = ba;
    __syncthreads();
    block_suffix_scan(sAr, sBr, sAa, sBa, tid);
    float2 c = car[blockIdx.x];
    float Sar = 1.f, Sbr = 0.f, Saa = 1.f, Sba = 0.f;
    if (tid + 1 < NT) { Sar = sAr[tid + 1]; Sbr = sBr[tid + 1]; Saa = sAa[tid + 1]; Sba = sBa[tid + 1]; }
    float yr = Sar * c.x + Sbr;   // ret state entering this thread's chunk
    float ya = Saa * c.y + Sba;   // adv state
    float retj[4], advj[4];
    float vn = vnext;
#pragma unroll
    for (int j = EPT - 1; j >= 0; --j) {
        float m = mm[j];
        float gm = GAMMA_F * m;
        yr = rr[j] + gm * yr;  retj[j] = yr;
        float delta = rr[j] + GAMMA_F * vn * m - vv[j];
        ya = delta + GL_F * m * ya;  advj[j] = ya;
        vn = vv[j];
    }
    *(float4*)(advo + g) = make_float4(advj[0], advj[1], advj[2], advj[3]);
    *(float4*)(reto + g) = make_float4(retj[0], retj[1], retj[2], retj[3]);
    // stat partials
    float sa = advj[0] + advj[1] + advj[2] + advj[3];
    float qa = advj[0]*advj[0] + advj[1]*advj[1] + advj[2]*advj[2] + advj[3]*advj[3];
    float sr = retj[0] + retj[1] + retj[2] + retj[3];
    float qr = retj[0]*retj[0] + retj[1]*retj[1] + retj[2]*retj[2] + retj[3]*retj[3];
    __syncthreads();
    sAr[tid] = sa; sBr[tid] = qa; sAa[tid] = sr; sBa[tid] = qr;
    __syncthreads();
    for (int s = NT / 2; s > 0; s >>= 1) {
        if (tid < s) {
            sAr[tid] += sAr[tid + s]; sBr[tid] += sBr[tid + s];
            sAa[tid] += sAa[tid + s]; sBa[tid] += sBa[tid + s];
        }
        __syncthreads();
    }
    if (tid == 0) {
        atomicAdd(&acc[0], (double)sAr[0]);
        atomicAdd(&acc[1], (double)sBr[0]);
        atomicAdd(&acc[2], (double)sAa[0]);
        atomicAdd(&acc[3], (double)sBa[0]);
    }
}

__global__ __launch_bounds__(NT) void k_loss(const float4* __restrict__ act,
                                             const float4* __restrict__ mu,
                                             const float4* __restrict__ lv,
                                             const float4* __restrict__ blp,
                                             const float* __restrict__ adv,
                                             const float* __restrict__ ret,
                                             const float* __restrict__ val,
                                             double* __restrict__ acc) {
    // stats (uniform scalar loads; every thread computes identically)
    double sa = acc[0], qa = acc[1], sr = acc[2], qr = acc[3];
    const double Td = (double)T_N;
    double va = (qa - sa * sa / Td) / (Td - 1.0);
    double vr = (qr - sr * sr / Td) / (Td - 1.0);
    float mean_a = (float)(sa / Td), mean_r = (float)(sr / Td);
    float inv_a = (float)(1.0 / (sqrt(va) + 1e-10));
    float inv_r = (float)(1.0 / (sqrt(vr) + 1e-10));

    float aacc = 0.f, cacc = 0.f;
    int stride = gridDim.x * blockDim.x;
    for (int t = blockIdx.x * blockDim.x + threadIdx.x; t < T_N; t += stride) {
        float4 a = act[t], m = mu[t], l = lv[t], b = blp[t];
        float x0 = -0.5f * (a.x - m.x) * (a.x - m.x) * expf(-l.x) - 0.5f * l.x;
        float x1 = -0.5f * (a.y - m.y) * (a.y - m.y) * expf(-l.y) - 0.5f * l.y;
        float x2 = -0.5f * (a.z - m.z) * (a.z - m.z) * expf(-l.z) - 0.5f * l.z;
        float x3 = -0.5f * (a.w - m.w) * (a.w - m.w) * expf(-l.w) - 0.5f * l.w;
        float X = (x0 + x1 + x2 + x3) - (b.x + b.y + b.z + b.w) - 2.f * LOG2PI_F;
        float ratio = expf(X);
        float rc = fminf(fmaxf(ratio, 0.8f), 1.2f);
        float an = (adv[t] - mean_a) * inv_a;
        aacc += fminf(ratio * an, rc * an);
        float rn = (ret[t] - mean_r) * inv_r;
        float d = val[t] - rn;
        float ad = fabsf(d);
        cacc += (ad < 1.f) ? 0.5f * d * d : ad - 0.5f;
    }
    __shared__ float sA[NT], sC[NT];
    int tid = threadIdx.x;
    sA[tid] = aacc; sC[tid] = cacc;
    __syncthreads();
    for (int s = NT / 2; s > 0; s >>= 1) {
        if (tid < s) { sA[tid] += sA[tid + s]; sC[tid] += sC[tid + s]; }
        __syncthreads();
    }
    if (tid == 0) {
        atomicAdd(&acc[4], (double)sA[0]);
        atomicAdd(&acc[5], (double)sC[0]);
    }
}

__global__ void k_final(const double* __restrict__ acc, float* __restrict__ out) {
    out[0] = (float)((-acc[4] + acc[5]) / (double)T_N);
}

extern "C" void kernel_launch(void* const* d_in, const int* in_sizes, int n_in,
                              void* d_out, int out_size, void* d_ws, size_t ws_size,
                              hipStream_t stream) {
    const float* rew = (const float*)d_in[0];
    const float* val = (const float*)d_in[1];
    const float* blp = (const float*)d_in[2];
    const float* act = (const float*)d_in[3];
    const float* mu  = (const float*)d_in[4];
    const float* lv  = (const float*)d_in[5];
    const int*   msk = (const int*)d_in[6];

    char* ws = (char*)d_ws;
    double* acc = (double*)ws;                                   // 6 doubles
    float4* blk = (float4*)(ws + 256);                           // NBLK * 16 B
    float2* car = (float2*)(ws + 256 + NBLK * 16);               // NBLK * 8 B
    float* adv  = (float*)(ws + 256 + NBLK * 16 + NBLK * 8);     // T floats (offset 49408, 16B-aligned)
    float* ret  = adv + T_N;                                     // T floats

    k_summ<<<NBLK, NT, 0, stream>>>(rew, val, msk, blk);
    k_carry<<<1, NT, 0, stream>>>(blk, car, acc);
    k_scan<<<NBLK, NT, 0, stream>>>(rew, val, msk, car, adv, ret, acc);
    k_loss<<<NBLK, NT, 0, stream>>>((const float4*)act, (const float4*)mu,
                                    (const float4*)lv, (const float4*)blp,
                                    adv, ret, val, acc);
    k_final<<<1, 1, 0, stream>>>(acc, (float*)d_out);
}

// Round 2
// 199.502 us; speedup vs baseline: 1.5491x; 1.5491x over previous
//
#include <hip/hip_runtime.h>
#include <math.h>

#define T_N 2097152
#define NBLK 2048
#define NT 256
#define EPT 4
#define CHUNK (NT * EPT)          // 1024 elements per block
#define GAMMA_F 0.99f
#define GL_F (0.99f * 0.95f)
#define LOG2PI_F 1.8378770664093453f

// ws layout (all slots rewritten every launch -> poison-safe):
//   ws +      0 : float stats[8]  (mean_a, inv_a, mean_r, inv_r)
//   ws +    256 : float4 blk[NBLK]    block affine summaries (Ar,Br,Aa,Ba)
//   ws +  33024 : float2 car[NBLK]    per-block entering carries (ret, adv)
//   ws +  49408 : float4 sblk[NBLK]   per-block stat partials (sa,qa,sr,qr)
//   ws +  82176 : float2 lblk[NBLK]   per-block loss partials (actor, critic)
//   ws +  98560 : float adv[T]
//   ws +  98560 + 4T : float ret[T]

struct Aff4 { float ar, br, aa, ba; };

__device__ __forceinline__ Aff4 aff_identity() { Aff4 o; o.ar = 1.f; o.br = 0.f; o.aa = 1.f; o.ba = 0.f; return o; }

// Apply R first (rightward in time), then L:  (L o R)(y) = L(R(y))
__device__ __forceinline__ Aff4 compose(const Aff4& L, const Aff4& R) {
    Aff4 o;
    o.ar = L.ar * R.ar;  o.br = fmaf(L.ar, R.br, L.br);
    o.aa = L.aa * R.aa;  o.ba = fmaf(L.aa, R.ba, L.ba);
    return o;
}

// Inclusive suffix scan across the 64-lane wave (Hillis-Steele, shuffle-based, no barriers).
__device__ __forceinline__ Aff4 wave_suffix_scan(Aff4 x, int lane) {
#pragma unroll
    for (int s = 1; s < 64; s <<= 1) {
        Aff4 o;
        o.ar = __shfl_down(x.ar, s, 64);
        o.br = __shfl_down(x.br, s, 64);
        o.aa = __shfl_down(x.aa, s, 64);
        o.ba = __shfl_down(x.ba, s, 64);
        if (lane + s < 64) x = compose(x, o);
    }
    return x;
}

// This thread's affine transform over its EPT elements (built right-to-left).
__device__ __forceinline__ Aff4 thread_transform(const float rr[4], const float vv[4],
                                                 const float mm[4], float vnext) {
    Aff4 x = aff_identity();
    float vn = vnext;
#pragma unroll
    for (int j = EPT - 1; j >= 0; --j) {
        float m = mm[j];
        float gm = GAMMA_F * m;
        x.br = fmaf(gm, x.br, rr[j]);  x.ar = gm * x.ar;              // ret: y = gm*y + r
        float delta = fmaf(GAMMA_F * vn, m, rr[j]) - vv[j];
        float gl = GL_F * m;
        x.ba = fmaf(gl, x.ba, delta);  x.aa = gl * x.aa;              // adv: y = gl*y + delta
        vn = vv[j];
    }
    return x;
}

__global__ __launch_bounds__(NT) void k_summ(const float* __restrict__ rew,
                                             const float* __restrict__ val,
                                             const int* __restrict__ msk,
                                             float4* __restrict__ blk) {
    int tid = threadIdx.x, lane = tid & 63, wv = tid >> 6;
    int g = blockIdx.x * CHUNK + tid * EPT;
    float4 r4 = *(const float4*)(rew + g);
    float4 v4 = *(const float4*)(val + g);
    int4 m4 = *(const int4*)(msk + g);
    float vnext = (g + EPT < T_N) ? val[g + EPT] : 0.f;
    float rr[4] = {r4.x, r4.y, r4.z, r4.w};
    float vv[4] = {v4.x, v4.y, v4.z, v4.w};
    float mm[4] = {(float)m4.x, (float)m4.y, (float)m4.z, (float)m4.w};
    Aff4 x = thread_transform(rr, vv, mm, vnext);
    Aff4 incl = wave_suffix_scan(x, lane);
    __shared__ Aff4 sW[4];
    if (lane == 0) sW[wv] = incl;    // wave total
    __syncthreads();
    if (tid == 0) {
        Aff4 t = sW[3];
        t = compose(sW[2], t); t = compose(sW[1], t); t = compose(sW[0], t);
        blk[blockIdx.x] = make_float4(t.ar, t.br, t.aa, t.ba);
    }
}

__global__ __launch_bounds__(NT) void k_carry(const float4* __restrict__ blk,
                                              float2* __restrict__ car) {
    int tid = threadIdx.x, lane = tid & 63, wv = tid >> 6;
    const int GPT = NBLK / NT;  // 8 summaries per thread
    Aff4 s[8];
#pragma unroll
    for (int p = 0; p < GPT; ++p) {
        float4 v = blk[tid * GPT + p];
        s[p].ar = v.x; s[p].br = v.y; s[p].aa = v.z; s[p].ba = v.w;
    }
    Aff4 gcomp = aff_identity();
#pragma unroll
    for (int p = GPT - 1; p >= 0; --p) gcomp = compose(s[p], gcomp);
    Aff4 incl = wave_suffix_scan(gcomp, lane);
    // exclusive suffix within wave
    Aff4 ex;
    ex.ar = __shfl_down(incl.ar, 1, 64);
    ex.br = __shfl_down(incl.br, 1, 64);
    ex.aa = __shfl_down(incl.aa, 1, 64);
    ex.ba = __shfl_down(incl.ba, 1, 64);
    if (lane == 63) ex = aff_identity();
    __shared__ Aff4 sW[4];
    if (lane == 0) sW[wv] = incl;
    __syncthreads();
    Aff4 tail = aff_identity();
    for (int w = 3; w > wv; --w) tail = compose(sW[w], tail);
    Aff4 H = compose(ex, tail);   // composition of all summaries after this thread's group
#pragma unroll
    for (int p = GPT - 1; p >= 0; --p) {
        car[tid * GPT + p] = make_float2(H.br, H.ba);   // carry entering block = H applied to 0
        H = compose(s[p], H);
    }
}

__global__ __launch_bounds__(NT) void k_scan(const float* __restrict__ rew,
                                             const float* __restrict__ val,
                                             const int* __restrict__ msk,
                                             const float2* __restrict__ car,
                                             float* __restrict__ advo,
                                             float* __restrict__ reto,
                                             float4* __restrict__ sblk) {
    int tid = threadIdx.x, lane = tid & 63, wv = tid >> 6;
    int g = blockIdx.x * CHUNK + tid * EPT;
    float4 r4 = *(const float4*)(rew + g);
    float4 v4 = *(const float4*)(val + g);
    int4 m4 = *(const int4*)(msk + g);
    float vnext = (g + EPT < T_N) ? val[g + EPT] : 0.f;
    float rr[4] = {r4.x, r4.y, r4.z, r4.w};
    float vv[4] = {v4.x, v4.y, v4.z, v4.w};
    float mm[4] = {(float)m4.x, (float)m4.y, (float)m4.z, (float)m4.w};
    Aff4 x = thread_transform(rr, vv, mm, vnext);
    Aff4 incl = wave_suffix_scan(x, lane);
    Aff4 ex;
    ex.ar = __shfl_down(incl.ar, 1, 64);
    ex.br = __shfl_down(incl.br, 1, 64);
    ex.aa = __shfl_down(incl.aa, 1, 64);
    ex.ba = __shfl_down(incl.ba, 1, 64);
    if (lane == 63) ex = aff_identity();
    __shared__ Aff4 sW[4];
    if (lane == 0) sW[wv] = incl;
    __syncthreads();
    Aff4 tail = aff_identity();
    for (int w = 3; w > wv; --w) tail = compose(sW[w], tail);
    ex = compose(ex, tail);       // transforms of all chunks after this thread within block
    float2 c = car[blockIdx.x];
    float yr = fmaf(ex.ar, c.x, ex.br);   // ret state entering this thread's chunk
    float ya = fmaf(ex.aa, c.y, ex.ba);   // adv state
    float retj[4], advj[4];
    float vn = vnext;
#pragma unroll
    for (int j = EPT - 1; j >= 0; --j) {
        float m = mm[j];
        float gm = GAMMA_F * m;
        yr = fmaf(gm, yr, rr[j]);  retj[j] = yr;
        float delta = fmaf(GAMMA_F * vn, m, rr[j]) - vv[j];
        ya = fmaf(GL_F * m, ya, delta);  advj[j] = ya;
        vn = vv[j];
    }
    *(float4*)(advo + g) = make_float4(advj[0], advj[1], advj[2], advj[3]);
    *(float4*)(reto + g) = make_float4(retj[0], retj[1], retj[2], retj[3]);
    // stat partials: sum & sumsq for adv and ret
    float sa = advj[0] + advj[1] + advj[2] + advj[3];
    float qa = advj[0]*advj[0] + advj[1]*advj[1] + advj[2]*advj[2] + advj[3]*advj[3];
    float sr = retj[0] + retj[1] + retj[2] + retj[3];
    float qr = retj[0]*retj[0] + retj[1]*retj[1] + retj[2]*retj[2] + retj[3]*retj[3];
#pragma unroll
    for (int s = 32; s > 0; s >>= 1) {
        sa += __shfl_xor(sa, s, 64);
        qa += __shfl_xor(qa, s, 64);
        sr += __shfl_xor(sr, s, 64);
        qr += __shfl_xor(qr, s, 64);
    }
    __shared__ float4 sS[4];
    if (lane == 0) sS[wv] = make_float4(sa, qa, sr, qr);
    __syncthreads();
    if (tid == 0) {
        float4 a = sS[0], b = sS[1], cc = sS[2], d = sS[3];
        sblk[blockIdx.x] = make_float4(a.x + b.x + cc.x + d.x, a.y + b.y + cc.y + d.y,
                                       a.z + b.z + cc.z + d.z, a.w + b.w + cc.w + d.w);
    }
}

__global__ __launch_bounds__(NT) void k_stats(const float4* __restrict__ sblk,
                                              float* __restrict__ stats) {
    int tid = threadIdx.x, lane = tid & 63, wv = tid >> 6;
    double sa = 0, qa = 0, sr = 0, qr = 0;
#pragma unroll
    for (int p = 0; p < NBLK / NT; ++p) {
        float4 v = sblk[tid * (NBLK / NT) + p];
        sa += v.x; qa += v.y; sr += v.z; qr += v.w;
    }
#pragma unroll
    for (int s = 32; s > 0; s >>= 1) {
        sa += __shfl_xor(sa, s, 64);
        qa += __shfl_xor(qa, s, 64);
        sr += __shfl_xor(sr, s, 64);
        qr += __shfl_xor(qr, s, 64);
    }
    __shared__ double sD[4][4];
    if (lane == 0) { sD[wv][0] = sa; sD[wv][1] = qa; sD[wv][2] = sr; sD[wv][3] = qr; }
    __syncthreads();
    if (tid == 0) {
        sa = sD[0][0] + sD[1][0] + sD[2][0] + sD[3][0];
        qa = sD[0][1] + sD[1][1] + sD[2][1] + sD[3][1];
        sr = sD[0][2] + sD[1][2] + sD[2][2] + sD[3][2];
        qr = sD[0][3] + sD[1][3] + sD[2][3] + sD[3][3];
        const double Td = (double)T_N;
        double va = (qa - sa * sa / Td) / (Td - 1.0);
        double vr = (qr - sr * sr / Td) / (Td - 1.0);
        stats[0] = (float)(sa / Td);
        stats[1] = (float)(1.0 / (sqrt(va) + 1e-10));
        stats[2] = (float)(sr / Td);
        stats[3] = (float)(1.0 / (sqrt(vr) + 1e-10));
    }
}

__global__ __launch_bounds__(NT) void k_loss(const float4* __restrict__ act,
                                             const float4* __restrict__ mu,
                                             const float4* __restrict__ lv,
                                             const float4* __restrict__ blp,
                                             const float* __restrict__ adv,
                                             const float* __restrict__ ret,
                                             const float* __restrict__ val,
                                             const float* __restrict__ stats,
                                             float2* __restrict__ lblk) {
    float mean_a = stats[0], inv_a = stats[1], mean_r = stats[2], inv_r = stats[3];
    float aacc = 0.f, cacc = 0.f;
    int stride = gridDim.x * blockDim.x;
    for (int t = blockIdx.x * blockDim.x + threadIdx.x; t < T_N; t += stride) {
        float4 a = act[t], m = mu[t], l = lv[t], b = blp[t];
        float x0 = -0.5f * (a.x - m.x) * (a.x - m.x) * expf(-l.x) - 0.5f * l.x;
        float x1 = -0.5f * (a.y - m.y) * (a.y - m.y) * expf(-l.y) - 0.5f * l.y;
        float x2 = -0.5f * (a.z - m.z) * (a.z - m.z) * expf(-l.z) - 0.5f * l.z;
        float x3 = -0.5f * (a.w - m.w) * (a.w - m.w) * expf(-l.w) - 0.5f * l.w;
        float X = (x0 + x1 + x2 + x3) - (b.x + b.y + b.z + b.w) - 2.f * LOG2PI_F;
        float ratio = expf(X);
        float rc = fminf(fmaxf(ratio, 0.8f), 1.2f);
        float an = (adv[t] - mean_a) * inv_a;
        aacc += fminf(ratio * an, rc * an);
        float rn = (ret[t] - mean_r) * inv_r;
        float d = val[t] - rn;
        float ad = fabsf(d);
        cacc += (ad < 1.f) ? 0.5f * d * d : ad - 0.5f;
    }
    int tid = threadIdx.x, lane = tid & 63, wv = tid >> 6;
#pragma unroll
    for (int s = 32; s > 0; s >>= 1) {
        aacc += __shfl_xor(aacc, s, 64);
        cacc += __shfl_xor(cacc, s, 64);
    }
    __shared__ float2 sL[4];
    if (lane == 0) sL[wv] = make_float2(aacc, cacc);
    __syncthreads();
    if (tid == 0) {
        lblk[blockIdx.x] = make_float2(sL[0].x + sL[1].x + sL[2].x + sL[3].x,
                                       sL[0].y + sL[1].y + sL[2].y + sL[3].y);
    }
}

__global__ __launch_bounds__(NT) void k_final(const float2* __restrict__ lblk,
                                              float* __restrict__ out) {
    int tid = threadIdx.x, lane = tid & 63, wv = tid >> 6;
    double ac = 0, cr = 0;
#pragma unroll
    for (int p = 0; p < NBLK / NT; ++p) {
        float2 v = lblk[tid * (NBLK / NT) + p];
        ac += v.x; cr += v.y;
    }
#pragma unroll
    for (int s = 32; s > 0; s >>= 1) {
        ac += __shfl_xor(ac, s, 64);
        cr += __shfl_xor(cr, s, 64);
    }
    __shared__ double sD[4][2];
    if (lane == 0) { sD[wv][0] = ac; sD[wv][1] = cr; }
    __syncthreads();
    if (tid == 0) {
        ac = sD[0][0] + sD[1][0] + sD[2][0] + sD[3][0];
        cr = sD[0][1] + sD[1][1] + sD[2][1] + sD[3][1];
        out[0] = (float)((-ac + cr) / (double)T_N);
    }
}

extern "C" void kernel_launch(void* const* d_in, const int* in_sizes, int n_in,
                              void* d_out, int out_size, void* d_ws, size_t ws_size,
                              hipStream_t stream) {
    const float* rew = (const float*)d_in[0];
    const float* val = (const float*)d_in[1];
    const float* blp = (const float*)d_in[2];
    const float* act = (const float*)d_in[3];
    const float* mu  = (const float*)d_in[4];
    const float* lv  = (const float*)d_in[5];
    const int*   msk = (const int*)d_in[6];

    char* ws = (char*)d_ws;
    float*  stats = (float*)ws;                         // 8 floats
    float4* blk   = (float4*)(ws + 256);                // NBLK*16
    float2* car   = (float2*)(ws + 256 + NBLK * 16);    // NBLK*8
    float4* sblk  = (float4*)(ws + 256 + NBLK * 24);    // NBLK*16
    float2* lblk  = (float2*)(ws + 256 + NBLK * 40);    // NBLK*8
    float*  adv   = (float*)(ws + 256 + NBLK * 48);     // T floats (offset 98560, 16B-aligned)
    float*  ret   = adv + T_N;                          // T floats

    k_summ <<<NBLK, NT, 0, stream>>>(rew, val, msk, blk);
    k_carry<<<1,    NT, 0, stream>>>(blk, car);
    k_scan <<<NBLK, NT, 0, stream>>>(rew, val, msk, car, adv, ret, sblk);
    k_stats<<<1,    NT, 0, stream>>>(sblk, stats);
    k_loss <<<NBLK, NT, 0, stream>>>((const float4*)act, (const float4*)mu,
                                     (const float4*)lv, (const float4*)blp,
                                     adv, ret, val, stats, lblk);
    k_final<<<1,    NT, 0, stream>>>(lblk, (float*)d_out);
}

// Round 4
// 193.037 us; speedup vs baseline: 1.6009x; 1.0335x over previous
//
#include <hip/hip_runtime.h>
#include <math.h>

#define T_N 2097152
#define NBS 1024               // scan grid
#define NT 256
#define EPT 8
#define CHUNK (NT * EPT)       // 2048 elements per scan block
#define NBL 1024               // loss grid
#define HALF (NBL * NT)        // 262144 threads
#define RPT 8                  // rows per thread in k_loss: RPT*HALF == T_N
#define GAMMA_F 0.99f
#define GL_F (0.99f * 0.95f)
#define LOG2PI_F 1.8378770664093453f

// ws layout (every slot rewritten each launch -> poison-safe):
//   ws +     0 : float4 blk[NBS]   block affine summaries (Ar,Br,Aa,Ba)
//   ws + 16384 : float2 car[NBS]   per-block entering carries (ret, adv)
//   ws + 24576 : float4 sblk[NBS]  per-block stat partials (sa,qa,sr,qr)
//   ws + 40960 : float2 lblk[NBL]  per-block loss partials (actor, critic)
//   ws + 49152 : float adv[T]
//   ws + 49152 + 4T : float ret[T]

struct Aff4 { float ar, br, aa, ba; };

__device__ __forceinline__ Aff4 aff_identity() { Aff4 o; o.ar = 1.f; o.br = 0.f; o.aa = 1.f; o.ba = 0.f; return o; }

// Apply R first (later in time), then L:  (L o R)(y) = L(R(y))
__device__ __forceinline__ Aff4 compose(const Aff4& L, const Aff4& R) {
    Aff4 o;
    o.ar = L.ar * R.ar;  o.br = fmaf(L.ar, R.br, L.br);
    o.aa = L.aa * R.aa;  o.ba = fmaf(L.aa, R.ba, L.ba);
    return o;
}

// Inclusive suffix scan across the 64-lane wave (no barriers).
__device__ __forceinline__ Aff4 wave_suffix_scan(Aff4 x, int lane) {
#pragma unroll
    for (int s = 1; s < 64; s <<= 1) {
        Aff4 o;
        o.ar = __shfl_down(x.ar, s, 64);
        o.br = __shfl_down(x.br, s, 64);
        o.aa = __shfl_down(x.aa, s, 64);
        o.ba = __shfl_down(x.ba, s, 64);
        if (lane + s < 64) x = compose(x, o);
    }
    return x;
}

// Thread's affine transform over its EPT contiguous elements (built right-to-left).
__device__ __forceinline__ Aff4 thread_transform(const float rr[EPT], const float vv[EPT],
                                                 const float mm[EPT], float vnext) {
    Aff4 x = aff_identity();
    float vn = vnext;
#pragma unroll
    for (int j = EPT - 1; j >= 0; --j) {
        float m = mm[j];
        float gm = GAMMA_F * m;
        x.br = fmaf(gm, x.br, rr[j]);  x.ar = gm * x.ar;              // ret: y = gm*y + r
        float delta = fmaf(GAMMA_F * vn, m, rr[j]) - vv[j];
        float gl = GL_F * m;
        x.ba = fmaf(gl, x.ba, delta);  x.aa = gl * x.aa;              // adv: y = gl*y + delta
        vn = vv[j];
    }
    return x;
}

__device__ __forceinline__ void load8(const float* __restrict__ rew,
                                      const float* __restrict__ val,
                                      const int* __restrict__ msk, int g,
                                      float rr[EPT], float vv[EPT], float mm[EPT],
                                      float& vnext) {
    float4 r0 = *(const float4*)(rew + g);
    float4 r1 = *(const float4*)(rew + g + 4);
    float4 v0 = *(const float4*)(val + g);
    float4 v1 = *(const float4*)(val + g + 4);
    int4 m0 = *(const int4*)(msk + g);
    int4 m1 = *(const int4*)(msk + g + 4);
    vnext = (g + EPT < T_N) ? val[g + EPT] : 0.f;
    rr[0]=r0.x; rr[1]=r0.y; rr[2]=r0.z; rr[3]=r0.w; rr[4]=r1.x; rr[5]=r1.y; rr[6]=r1.z; rr[7]=r1.w;
    vv[0]=v0.x; vv[1]=v0.y; vv[2]=v0.z; vv[3]=v0.w; vv[4]=v1.x; vv[5]=v1.y; vv[6]=v1.z; vv[7]=v1.w;
    mm[0]=(float)m0.x; mm[1]=(float)m0.y; mm[2]=(float)m0.z; mm[3]=(float)m0.w;
    mm[4]=(float)m1.x; mm[5]=(float)m1.y; mm[6]=(float)m1.z; mm[7]=(float)m1.w;
}

__global__ __launch_bounds__(NT) void k_summ(const float* __restrict__ rew,
                                             const float* __restrict__ val,
                                             const int* __restrict__ msk,
                                             float4* __restrict__ blk) {
    int tid = threadIdx.x, lane = tid & 63, wv = tid >> 6;
    int g = blockIdx.x * CHUNK + tid * EPT;
    float rr[EPT], vv[EPT], mm[EPT], vnext;
    load8(rew, val, msk, g, rr, vv, mm, vnext);
    Aff4 x = thread_transform(rr, vv, mm, vnext);
    Aff4 incl = wave_suffix_scan(x, lane);
    __shared__ Aff4 sW[4];
    if (lane == 0) sW[wv] = incl;    // wave total
    __syncthreads();
    if (tid == 0) {
        Aff4 t = sW[3];
        t = compose(sW[2], t); t = compose(sW[1], t); t = compose(sW[0], t);
        blk[blockIdx.x] = make_float4(t.ar, t.br, t.aa, t.ba);
    }
}

__global__ __launch_bounds__(NT) void k_carry(const float4* __restrict__ blk,
                                              float2* __restrict__ car) {
    int tid = threadIdx.x, lane = tid & 63, wv = tid >> 6;
    const int GPT = NBS / NT;  // 4 summaries per thread
    Aff4 s[GPT];
#pragma unroll
    for (int p = 0; p < GPT; ++p) {
        float4 v = blk[tid * GPT + p];
        s[p].ar = v.x; s[p].br = v.y; s[p].aa = v.z; s[p].ba = v.w;
    }
    Aff4 gcomp = aff_identity();
#pragma unroll
    for (int p = GPT - 1; p >= 0; --p) gcomp = compose(s[p], gcomp);
    Aff4 incl = wave_suffix_scan(gcomp, lane);
    Aff4 ex;
    ex.ar = __shfl_down(incl.ar, 1, 64);
    ex.br = __shfl_down(incl.br, 1, 64);
    ex.aa = __shfl_down(incl.aa, 1, 64);
    ex.ba = __shfl_down(incl.ba, 1, 64);
    if (lane == 63) ex = aff_identity();
    __shared__ Aff4 sW[4];
    if (lane == 0) sW[wv] = incl;
    __syncthreads();
    Aff4 tail = aff_identity();
    for (int w = 3; w > wv; --w) tail = compose(sW[w], tail);
    Aff4 H = compose(ex, tail);   // composition of all summaries after this thread's group
#pragma unroll
    for (int p = GPT - 1; p >= 0; --p) {
        car[tid * GPT + p] = make_float2(H.br, H.ba);   // carry entering block = H(0)
        H = compose(s[p], H);
    }
}

__global__ __launch_bounds__(NT) void k_scan(const float* __restrict__ rew,
                                             const float* __restrict__ val,
                                             const int* __restrict__ msk,
                                             const float2* __restrict__ car,
                                             float* __restrict__ advo,
                                             float* __restrict__ reto,
                                             float4* __restrict__ sblk) {
    int tid = threadIdx.x, lane = tid & 63, wv = tid >> 6;
    int g = blockIdx.x * CHUNK + tid * EPT;
    float rr[EPT], vv[EPT], mm[EPT], vnext;
    load8(rew, val, msk, g, rr, vv, mm, vnext);
    Aff4 x = thread_transform(rr, vv, mm, vnext);
    Aff4 incl = wave_suffix_scan(x, lane);
    Aff4 ex;
    ex.ar = __shfl_down(incl.ar, 1, 64);
    ex.br = __shfl_down(incl.br, 1, 64);
    ex.aa = __shfl_down(incl.aa, 1, 64);
    ex.ba = __shfl_down(incl.ba, 1, 64);
    if (lane == 63) ex = aff_identity();
    __shared__ Aff4 sW[4];
    if (lane == 0) sW[wv] = incl;
    __syncthreads();
    Aff4 tail = aff_identity();
    for (int w = 3; w > wv; --w) tail = compose(sW[w], tail);
    ex = compose(ex, tail);       // transforms of all chunks after this thread within block
    float2 c = car[blockIdx.x];
    float yr = fmaf(ex.ar, c.x, ex.br);   // ret state entering this thread's chunk
    float ya = fmaf(ex.aa, c.y, ex.ba);   // adv state
    float retj[EPT], advj[EPT];
    float vn = vnext;
#pragma unroll
    for (int j = EPT - 1; j >= 0; --j) {
        float m = mm[j];
        float gm = GAMMA_F * m;
        yr = fmaf(gm, yr, rr[j]);  retj[j] = yr;
        float delta = fmaf(GAMMA_F * vn, m, rr[j]) - vv[j];
        ya = fmaf(GL_F * m, ya, delta);  advj[j] = ya;
        vn = vv[j];
    }
    *(float4*)(advo + g)     = make_float4(advj[0], advj[1], advj[2], advj[3]);
    *(float4*)(advo + g + 4) = make_float4(advj[4], advj[5], advj[6], advj[7]);
    *(float4*)(reto + g)     = make_float4(retj[0], retj[1], retj[2], retj[3]);
    *(float4*)(reto + g + 4) = make_float4(retj[4], retj[5], retj[6], retj[7]);
    float sa = 0.f, qa = 0.f, sr = 0.f, qr = 0.f;
#pragma unroll
    for (int j = 0; j < EPT; ++j) {
        sa += advj[j]; qa = fmaf(advj[j], advj[j], qa);
        sr += retj[j]; qr = fmaf(retj[j], retj[j], qr);
    }
#pragma unroll
    for (int s = 32; s > 0; s >>= 1) {
        sa += __shfl_xor(sa, s, 64);
        qa += __shfl_xor(qa, s, 64);
        sr += __shfl_xor(sr, s, 64);
        qr += __shfl_xor(qr, s, 64);
    }
    __shared__ float4 sS[4];
    if (lane == 0) sS[wv] = make_float4(sa, qa, sr, qr);
    __syncthreads();
    if (tid == 0) {
        float4 a = sS[0], b = sS[1], cc = sS[2], d = sS[3];
        sblk[blockIdx.x] = make_float4(a.x + b.x + cc.x + d.x, a.y + b.y + cc.y + d.y,
                                       a.z + b.z + cc.z + d.z, a.w + b.w + cc.w + d.w);
    }
}

__global__ __launch_bounds__(NT) void k_loss(const float4* __restrict__ act,
                                             const float4* __restrict__ mu,
                                             const float4* __restrict__ lv,
                                             const float4* __restrict__ blp,
                                             const float* __restrict__ adv,
                                             const float* __restrict__ ret,
                                             const float* __restrict__ val,
                                             const float4* __restrict__ sblk,
                                             float2* __restrict__ lblk) {
    int tid = threadIdx.x, lane = tid & 63, wv = tid >> 6;
    // ---- redundant per-block stats reduce over sblk[1024] (L2-resident) ----
    double sa = 0, qa = 0, sr = 0, qr = 0;
#pragma unroll
    for (int p = 0; p < NBS / NT; ++p) {
        float4 v = sblk[tid + p * NT];
        sa += v.x; qa += v.y; sr += v.z; qr += v.w;
    }
#pragma unroll
    for (int s = 32; s > 0; s >>= 1) {
        sa += __shfl_xor(sa, s, 64);
        qa += __shfl_xor(qa, s, 64);
        sr += __shfl_xor(sr, s, 64);
        qr += __shfl_xor(qr, s, 64);
    }
    __shared__ double sD[4][4];
    if (lane == 0) { sD[wv][0] = sa; sD[wv][1] = qa; sD[wv][2] = sr; sD[wv][3] = qr; }
    __syncthreads();
    sa = sD[0][0] + sD[1][0] + sD[2][0] + sD[3][0];
    qa = sD[0][1] + sD[1][1] + sD[2][1] + sD[3][1];
    sr = sD[0][2] + sD[1][2] + sD[2][2] + sD[3][2];
    qr = sD[0][3] + sD[1][3] + sD[2][3] + sD[3][3];
    const double Td = (double)T_N;
    float mean_a = (float)(sa / Td);
    float inv_a  = (float)(1.0 / (sqrt((qa - sa * sa / Td) / (Td - 1.0)) + 1e-10));
    float mean_r = (float)(sr / Td);
    float inv_r  = (float)(1.0 / (sqrt((qr - sr * sr / Td) / (Td - 1.0)) + 1e-10));

    // ---- main loss: RPT(=8) float4-rows per thread, strided by HALF (coalesced),
    //      processed as 2 passes of 4 rows with loads clustered per pass ----
    int base = blockIdx.x * NT + tid;     // in [0, HALF)
    float aacc = 0.f, cacc = 0.f;
#pragma unroll
    for (int h = 0; h < 2; ++h) {
        float4 A[4], M[4], L[4], B[4];
        float AD[4], RT[4], VL[4];
#pragma unroll
        for (int k = 0; k < 4; ++k) {
            int r = base + (h * 4 + k) * HALF;
            A[k] = act[r]; M[k] = mu[r]; L[k] = lv[r]; B[k] = blp[r];
            AD[k] = adv[r]; RT[k] = ret[r]; VL[k] = val[r];
        }
#pragma unroll
        for (int k = 0; k < 4; ++k) {
            float4 a = A[k], m = M[k], l = L[k], b = B[k];
            float x0 = -0.5f * (a.x - m.x) * (a.x - m.x) * expf(-l.x) - 0.5f * l.x;
            float x1 = -0.5f * (a.y - m.y) * (a.y - m.y) * expf(-l.y) - 0.5f * l.y;
            float x2 = -0.5f * (a.z - m.z) * (a.z - m.z) * expf(-l.z) - 0.5f * l.z;
            float x3 = -0.5f * (a.w - m.w) * (a.w - m.w) * expf(-l.w) - 0.5f * l.w;
            float X = (x0 + x1 + x2 + x3) - (b.x + b.y + b.z + b.w) - 2.f * LOG2PI_F;
            float ratio = expf(X);
            float rc = fminf(fmaxf(ratio, 0.8f), 1.2f);
            float an = (AD[k] - mean_a) * inv_a;
            aacc += fminf(ratio * an, rc * an);
            float rn = (RT[k] - mean_r) * inv_r;
            float d = VL[k] - rn;
            float adx = fabsf(d);
            cacc += (adx < 1.f) ? 0.5f * d * d : adx - 0.5f;
        }
    }
#pragma unroll
    for (int s = 32; s > 0; s >>= 1) {
        aacc += __shfl_xor(aacc, s, 64);
        cacc += __shfl_xor(cacc, s, 64);
    }
    __shared__ float2 sL[4];
    if (lane == 0) sL[wv] = make_float2(aacc, cacc);
    __syncthreads();
    if (tid == 0) {
        lblk[blockIdx.x] = make_float2(sL[0].x + sL[1].x + sL[2].x + sL[3].x,
                                       sL[0].y + sL[1].y + sL[2].y + sL[3].y);
    }
}

__global__ __launch_bounds__(NT) void k_final(const float2* __restrict__ lblk,
                                              float* __restrict__ out) {
    int tid = threadIdx.x, lane = tid & 63, wv = tid >> 6;
    double ac = 0, cr = 0;
#pragma unroll
    for (int p = 0; p < NBL / NT; ++p) {
        float2 v = lblk[tid + p * NT];
        ac += v.x; cr += v.y;
    }
#pragma unroll
    for (int s = 32; s > 0; s >>= 1) {
        ac += __shfl_xor(ac, s, 64);
        cr += __shfl_xor(cr, s, 64);
    }
    __shared__ double sD[4][2];
    if (lane == 0) { sD[wv][0] = ac; sD[wv][1] = cr; }
    __syncthreads();
    if (tid == 0) {
        ac = sD[0][0] + sD[1][0] + sD[2][0] + sD[3][0];
        cr = sD[0][1] + sD[1][1] + sD[2][1] + sD[3][1];
        out[0] = (float)((-ac + cr) / (double)T_N);
    }
}

extern "C" void kernel_launch(void* const* d_in, const int* in_sizes, int n_in,
                              void* d_out, int out_size, void* d_ws, size_t ws_size,
                              hipStream_t stream) {
    const float* rew = (const float*)d_in[0];
    const float* val = (const float*)d_in[1];
    const float* blp = (const float*)d_in[2];
    const float* act = (const float*)d_in[3];
    const float* mu  = (const float*)d_in[4];
    const float* lv  = (const float*)d_in[5];
    const int*   msk = (const int*)d_in[6];

    char* ws = (char*)d_ws;
    float4* blk  = (float4*)(ws);                // 16384 B
    float2* car  = (float2*)(ws + 16384);        //  8192 B
    float4* sblk = (float4*)(ws + 24576);        // 16384 B
    float2* lblk = (float2*)(ws + 40960);        //  8192 B
    float*  adv  = (float*)(ws + 49152);         // T floats
    float*  ret  = adv + T_N;                    // T floats

    k_summ <<<NBS, NT, 0, stream>>>(rew, val, msk, blk);
    k_carry<<<1,   NT, 0, stream>>>(blk, car);
    k_scan <<<NBS, NT, 0, stream>>>(rew, val, msk, car, adv, ret, sblk);
    k_loss <<<NBL, NT, 0, stream>>>((const float4*)act, (const float4*)mu,
                                    (const float4*)lv, (const float4*)blp,
                                    adv, ret, val, sblk, lblk);
    k_final<<<1,   NT, 0, stream>>>(lblk, (float*)d_out);
}